// Round 5
// baseline (257.160 us; speedup 1.0000x reference)
//
#include <hip/hip_runtime.h>

#define POOL 7
#define IMG_W 256
#define IMG_C 512
#define NUM_ROIS 1024

typedef float f4 __attribute__((ext_vector_type(4)));

// ---------------- kernel 1: spatial counting-sort of ROI indices ----------
// Key = 32x32-px tile of (x1,y1), row-major: 8x8 = 64 buckets. One block,
// 1024 threads. Within-bucket order nondeterministic (LDS atomics) —
// harmless: main kernel writes out[roi] exactly once, any order.
// Emits pre-gathered sorted descriptors; roi index packed into .w
// ((y2<<10)|roi) so the pool kernel needs ONE uniform 16B load per block.
__global__ __launch_bounds__(1024) void sort_rois_kernel(
    const int* __restrict__ rois, int4* __restrict__ sdesc)
{
    __shared__ int hist[64];
    __shared__ int base[64];
    const int tid = threadIdx.x;

    if (tid < 64) hist[tid] = 0;
    __syncthreads();

    const int4 rb = ((const int4*)rois)[tid];
    const int key = ((rb.y >> 5) << 3) | (rb.x >> 5);
    const int rank = atomicAdd(&hist[key], 1);
    __syncthreads();

    // wave-parallel exclusive prefix scan over the 64 buckets (one wave)
    if (tid < 64) {
        const int v = hist[tid];
        int inc = v;
#pragma unroll
        for (int d = 1; d < 64; d <<= 1) {
            const int n = __shfl_up(inc, d, 64);
            if (tid >= d) inc += n;
        }
        base[tid] = inc - v;
    }
    __syncthreads();

    const int dst = base[key] + rank;
    sdesc[dst] = (int4){rb.x, rb.y, rb.z, (rb.w << 10) | tid};
}

// ---------------- kernel 2: ROI pooling, ONE BLOCK PER ROI ----------------
// 1024 blocks x 128 threads. XCD i (bid&7) owns sorted chunk
// [i*128,(i+1)*128) — spatially adjacent ROIs stay on one XCD's L2.
// The whole ROI (7x7 outputs, 14x14 sample grid, ~392 KB of reads) is
// processed by one block: 7x fewer blocks/descriptor-loads than the
// per-(roi,py) version, column indices computed once, and the block
// streams the ROI's image region as one contiguous sweep (better DRAM
// page + L2 locality than 7 interleaved sibling blocks).
// Per-py body keeps the R2 max-MLP form: 28 clustered loads into
// statically-indexed register arrays, then weighted sums + NT stores.
// #pragma unroll 1 on the py loop keeps VGPR ~ R2 level (no 7x blowup).
__global__ __launch_bounds__(128, 2) void roi_pool_kernel(
    const float* __restrict__ img,
    const int4*  __restrict__ sdesc,
    float*       __restrict__ out)
{
    const int bid  = blockIdx.x;           // 0..1023
    const int xcd  = bid & 7;
    const int sloc = bid >> 3;             // 0..127: position within chunk
    const int sidx = xcd * (NUM_ROIS / 8) + sloc;   // sorted position

    const int4 rb = sdesc[sidx];
    const int x1  = __builtin_amdgcn_readfirstlane(rb.x);
    const int y1  = __builtin_amdgcn_readfirstlane(rb.y);
    const int x2  = __builtin_amdgcn_readfirstlane(rb.z);
    const int w2  = __builtin_amdgcn_readfirstlane(rb.w);
    const int y2  = w2 >> 10;
    const int roi = w2 & 1023;

    const float h = (float)(y2 - y1);
    const float w = (float)(x2 - x1);
    const float sy = h / (float)POOL;      // reference numerics: h/P, then py*(h/P)
    const float sx = w / (float)POOL;

    const size_t rowstride = (size_t)IMG_W * IMG_C;
    const int t = threadIdx.x;             // 0..127
    const int cmax = max(x2 - x1 - 1, 0);
    const int rmax = max(y2 - y1 - 1, 0);

    // ---- per-ROI column indices + weights (uniform, computed ONCE)
    int   c0a[POOL], c1a[POOL];
    float wxa[POOL];
#pragma unroll
    for (int px = 0; px < POOL; ++px) {
        const float xs = (float)px * sx;
        const int   x0 = (int)floorf(xs);
        c0a[px] = x1 + x0;
        c1a[px] = x1 + min(x0 + 1, cmax);
        wxa[px] = xs - (float)x0;
    }

    f4* obase = (f4*)out + (size_t)roi * (POOL * POOL) * (IMG_C / 4) + t;

#pragma unroll 1
    for (int py = 0; py < POOL; ++py) {
        const float ys = (float)py * sy;
        const int   y0 = (int)floorf(ys);
        const int   y1i = min(y0 + 1, rmax);
        const float wy = ys - (float)y0;

        const float* row0 = img + (size_t)(y1 + y0)  * rowstride;
        const float* row1 = img + (size_t)(y1 + y1i) * rowstride;

        // phase A: all 28 loads of this py, clustered, static indices
        f4 v00[POOL], v01[POOL], v10[POOL], v11[POOL];
#pragma unroll
        for (int px = 0; px < POOL; ++px) {
            v00[px] = ((const f4*)(row0 + (size_t)c0a[px] * IMG_C))[t];
            v01[px] = ((const f4*)(row0 + (size_t)c1a[px] * IMG_C))[t];
            v10[px] = ((const f4*)(row1 + (size_t)c0a[px] * IMG_C))[t];
            v11[px] = ((const f4*)(row1 + (size_t)c1a[px] * IMG_C))[t];
        }

        // phase B: weighted sums + NT stores
#pragma unroll
        for (int px = 0; px < POOL; ++px) {
            const float wx = wxa[px];
            const float w00 = (1.0f - wy) * (1.0f - wx);
            const float w01 = (1.0f - wy) * wx;
            const float w10 = wy * (1.0f - wx);
            const float w11 = wy * wx;
            f4 o = v00[px] * w00 + v01[px] * w01 + v10[px] * w10 + v11[px] * w11;
            __builtin_nontemporal_store(o, obase + (py * POOL + px) * (IMG_C / 4));
        }
    }
}

extern "C" void kernel_launch(void* const* d_in, const int* in_sizes, int n_in,
                              void* d_out, int out_size, void* d_ws, size_t ws_size,
                              hipStream_t stream) {
    const float* img  = (const float*)d_in[0];
    const int*   rois = (const int*)d_in[1];
    float* out = (float*)d_out;
    int4* sdesc = (int4*)d_ws;             // 1024 int4, rewritten every call

    sort_rois_kernel<<<1, 1024, 0, stream>>>(rois, sdesc);
    roi_pool_kernel<<<NUM_ROIS, 128, 0, stream>>>(img, sdesc, out);
}

// Round 8
// 234.406 us; speedup vs baseline: 1.0971x; 1.0971x over previous
//
#include <hip/hip_runtime.h>

#define POOL 7
#define IMG_W 256
#define IMG_C 512
#define NUM_ROIS 1024

typedef float f4 __attribute__((ext_vector_type(4)));

// ---------------- kernel 1: spatial counting-sort of ROI indices ----------
// Key = 32x32-px tile of (x1,y1), row-major: 8x8 = 64 buckets. One block,
// 1024 threads. Within-bucket order nondeterministic (LDS atomics) —
// harmless: main kernel writes out[roi] exactly once, any order.
// Emits pre-gathered sorted descriptors; roi index packed into .w
// ((y2<<10)|roi) so the pool kernel needs ONE uniform 16B load per block.
__global__ __launch_bounds__(1024) void sort_rois_kernel(
    const int* __restrict__ rois, int4* __restrict__ sdesc)
{
    __shared__ int hist[64];
    __shared__ int base[64];
    const int tid = threadIdx.x;

    if (tid < 64) hist[tid] = 0;
    __syncthreads();

    const int4 rb = ((const int4*)rois)[tid];
    const int key = ((rb.y >> 5) << 3) | (rb.x >> 5);
    const int rank = atomicAdd(&hist[key], 1);
    __syncthreads();

    // wave-parallel exclusive prefix scan over the 64 buckets (one wave)
    if (tid < 64) {
        const int v = hist[tid];
        int inc = v;
#pragma unroll
        for (int d = 1; d < 64; d <<= 1) {
            const int n = __shfl_up(inc, d, 64);
            if (tid >= d) inc += n;
        }
        base[tid] = inc - v;
    }
    __syncthreads();

    const int dst = base[key] + rank;
    sdesc[dst] = (int4){rb.x, rb.y, rb.z, (rb.w << 10) | tid};
}

// ---------------- kernel 2: ROI pooling, per-(roi,py), PINNED 28-load MLP -
// 7168 blocks x 128 threads (restores ~28 blocks/CU — R5 showed 1024
// blocks -> 18% occupancy regression). XCD i (bid&7) owns sorted chunk
// [i*128,(i+1)*128).
// R5 counter evidence: VGPR_Count=40 proved the compiler re-serializes
// the "clustered" 28 loads into ~4-load bursts to save registers —
// every prior MLP probe was out-of-regime. Fix: asm volatile "+v" pins
// on all 28 f4 destinations between load phase and compute phase. The
// compiler cannot sink a load past an asm that redefines its dest, so
// all 28 loads (28 KB/wave) are issued before one vmcnt drain.
// Expect VGPR ~150: at __launch_bounds__(128,2) the cap is 256, no spill;
// occupancy ~3 waves/SIMD is ample (7168 blocks deep grid).
__global__ __launch_bounds__(128, 2) void roi_pool_kernel(
    const float* __restrict__ img,
    const int4*  __restrict__ sdesc,
    float*       __restrict__ out)
{
    const int bid  = blockIdx.x;           // 0..7167
    const int xcd  = bid & 7;
    const int slot = bid >> 3;             // 0..895
    const int sloc = slot / POOL;          // 0..127: position within chunk
    const int py   = slot - sloc * POOL;   // 0..6
    const int sidx = xcd * (NUM_ROIS / 8) + sloc;   // sorted position

    const int4 rb = sdesc[sidx];
    const int x1  = __builtin_amdgcn_readfirstlane(rb.x);
    const int y1  = __builtin_amdgcn_readfirstlane(rb.y);
    const int x2  = __builtin_amdgcn_readfirstlane(rb.z);
    const int w2  = __builtin_amdgcn_readfirstlane(rb.w);
    const int y2  = w2 >> 10;
    const int roi = w2 & 1023;

    const float h = (float)(y2 - y1);
    const float w = (float)(x2 - x1);
    const float sy = h / (float)POOL;      // reference numerics: h/P, then py*(h/P)
    const float sx = w / (float)POOL;

    const float ys = (float)py * sy;
    const int   y0 = (int)floorf(ys);
    const int   y1i = min(y0 + 1, max(y2 - y1 - 1, 0));
    const float wy = ys - (float)y0;

    const size_t rowstride = (size_t)IMG_W * IMG_C;
    const float* row0 = img + (size_t)(y1 + y0)  * rowstride;
    const float* row1 = img + (size_t)(y1 + y1i) * rowstride;

    const int t = threadIdx.x;             // 0..127
    const int cmax = max(x2 - x1 - 1, 0);

    // ---- column indices + weights (uniform per block)
    int   c0a[POOL], c1a[POOL];
    float wxa[POOL];
#pragma unroll
    for (int px = 0; px < POOL; ++px) {
        const float xs = (float)px * sx;
        const int   x0 = (int)floorf(xs);
        c0a[px] = x1 + x0;
        c1a[px] = x1 + min(x0 + 1, cmax);
        wxa[px] = xs - (float)x0;
    }

    // ---- phase A: issue all 28 loads
    f4 v00[POOL], v01[POOL], v10[POOL], v11[POOL];
#pragma unroll
    for (int px = 0; px < POOL; ++px) {
        v00[px] = ((const f4*)(row0 + (size_t)c0a[px] * IMG_C))[t];
        v01[px] = ((const f4*)(row0 + (size_t)c1a[px] * IMG_C))[t];
        v10[px] = ((const f4*)(row1 + (size_t)c0a[px] * IMG_C))[t];
        v11[px] = ((const f4*)(row1 + (size_t)c1a[px] * IMG_C))[t];
    }

    // ---- pin: all 28 destinations must be materialized HERE.
    // Loads cannot sink below these asms; register allocator must keep
    // 112 VGPRs live -> all 28 loads outstanding simultaneously.
    asm volatile("" :
        "+v"(v00[0]), "+v"(v00[1]), "+v"(v00[2]), "+v"(v00[3]),
        "+v"(v00[4]), "+v"(v00[5]), "+v"(v00[6]),
        "+v"(v01[0]), "+v"(v01[1]), "+v"(v01[2]), "+v"(v01[3]),
        "+v"(v01[4]), "+v"(v01[5]), "+v"(v01[6]));
    asm volatile("" :
        "+v"(v10[0]), "+v"(v10[1]), "+v"(v10[2]), "+v"(v10[3]),
        "+v"(v10[4]), "+v"(v10[5]), "+v"(v10[6]),
        "+v"(v11[0]), "+v"(v11[1]), "+v"(v11[2]), "+v"(v11[3]),
        "+v"(v11[4]), "+v"(v11[5]), "+v"(v11[6]));

    // ---- phase B: weighted sums + NT stores
    f4* obase = (f4*)out + ((size_t)roi * (POOL * POOL) + (size_t)py * POOL) * (IMG_C / 4) + t;
#pragma unroll
    for (int px = 0; px < POOL; ++px) {
        const float wx = wxa[px];
        const float w00 = (1.0f - wy) * (1.0f - wx);
        const float w01 = (1.0f - wy) * wx;
        const float w10 = wy * (1.0f - wx);
        const float w11 = wy * wx;
        f4 o = v00[px] * w00 + v01[px] * w01 + v10[px] * w10 + v11[px] * w11;
        __builtin_nontemporal_store(o, obase + px * (IMG_C / 4));
    }
}

extern "C" void kernel_launch(void* const* d_in, const int* in_sizes, int n_in,
                              void* d_out, int out_size, void* d_ws, size_t ws_size,
                              hipStream_t stream) {
    const float* img  = (const float*)d_in[0];
    const int*   rois = (const int*)d_in[1];
    float* out = (float*)d_out;
    int4* sdesc = (int4*)d_ws;             // 1024 int4, rewritten every call

    sort_rois_kernel<<<1, 1024, 0, stream>>>(rois, sdesc);
    roi_pool_kernel<<<NUM_ROIS * POOL, 128, 0, stream>>>(img, sdesc, out);
}